// Round 2
// baseline (462.260 us; speedup 1.0000x reference)
//
#include <hip/hip_runtime.h>

#define NN 100000
#define NE 800000
#define BCAP 32  // bucket capacity per dst; deg ~ Poisson(8), P(deg>32) ~ 2.5e-11/node

static constexpr int NBT = NN / 32;      // dense-kernel blocks (32 nodes) = 3125, exact
static constexpr int NP1 = NN + 1;       // h rows per slab incl. zero pad row

typedef __attribute__((ext_vector_type(8))) short short8;
typedef __attribute__((ext_vector_type(4))) float f32x4;
typedef __attribute__((ext_vector_type(2))) float f32x2;
typedef __attribute__((ext_vector_type(4))) int int4v;
typedef __attribute__((ext_vector_type(4))) unsigned int uint4v;

__device__ __forceinline__ unsigned short f2bf(float f) {
  unsigned int u = __float_as_uint(f);
  u += 0x7fffu + ((u >> 16) & 1u);
  return (unsigned short)(u >> 16);
}
__device__ __forceinline__ float bflo(unsigned int u) { return __uint_as_float(u << 16); }
__device__ __forceinline__ float bfhi(unsigned int u) { return __uint_as_float(u & 0xffff0000u); }

// ---------------------------------------------------------------------------
// h layout is SLAB-MAJOR: h[s][node][16 feats], s = feat>>4, 32B per node-slab
// row. Slab s is a contiguous 3.2MB region; k_gather pins slab s to XCD s via
// blockIdx&7 (round-robin workgroup->XCD dispatch), so each XCD's gather
// working set fits its 4MiB L2. element index of (node, feat):
//   ((feat>>4)*NP1 + node)*16 + (feat&15)
// ---------------------------------------------------------------------------

// ------------- fused prep+fill: x->bf16 slab-major, W->bf16 B-frag, CSR fill ----------
// Also zeroes pad row NN of all three h buffers (branchless-gather target).

__global__ void k_prep_fill(const float* __restrict__ x, unsigned short* __restrict__ hb,
                            unsigned short* __restrict__ hb1, unsigned short* __restrict__ hb2,
                            const int* __restrict__ ei,
                            int* __restrict__ cnt, int* __restrict__ col,
                            const float* __restrict__ Wl, const float* __restrict__ Wr,
                            unsigned short* __restrict__ Wb, const float* __restrict__ Wf,
                            unsigned short* __restrict__ Wfb) {
  int i = blockIdx.x * 256 + threadIdx.x;
  long long base = (long long)i * 4;
  if (base < (long long)NN * 128) {
    float4 v = *(const float4*)(x + base);
    unsigned long long pk = (unsigned long long)f2bf(v.x) |
                            ((unsigned long long)f2bf(v.y) << 16) |
                            ((unsigned long long)f2bf(v.z) << 32) |
                            ((unsigned long long)f2bf(v.w) << 48);
    int node = i >> 5;
    int fb = (i & 31) * 4;  // 4 consecutive feats, all inside one 16-feat slab
    size_t e = ((size_t)(fb >> 4) * NP1 + node) * 16 + (fb & 15);
    *(unsigned long long*)(hb + e) = pk;
  } else if (i < NN * 32 + 96) {
    // zero pad row NN (8 slabs x 32B = 32 u64) in all three buffers
    int k = i - NN * 32;
    unsigned short* bp = (k < 32) ? hb : (k < 64 ? hb1 : hb2);
    int r = k & 31;
    *((unsigned long long*)bp + ((size_t)(r >> 2) * NP1 + NN) * 4 + (r & 3)) = 0ull;
  }
  if (i < NE) {
    int d = ei[i];
    int pos = atomicAdd(&cnt[d], 1);
    if (pos < BCAP) col[(size_t)d * BCAP + pos] = ei[NE + i];
  }
  if (i < 3 * 16384) {
    int layer = i >> 14, r = i & 16383;
    int j = r >> 7, k = r & 127;
    int c = k >> 5, q = (k >> 3) & 3, jj = k & 7, jt = j >> 4, j16 = j & 15;
    int slot = (c * 8 + jt) * 512 + (q * 16 + j16) * 8 + jj;
    Wb[layer * 32768 + slot] = f2bf(Wl[i]);
    Wb[layer * 32768 + 16384 + slot] = f2bf(Wr[i]);
  } else if (i < 3 * 16384 + 8192) {
    int idx = i - 3 * 16384;
    int j = idx >> 7, k = idx & 127;
    int c = k >> 5, q = (k >> 3) & 3, jj = k & 7, jt = j >> 4, j16 = j & 15;
    Wfb[(c * 4 + jt) * 512 + (q * 16 + j16) * 8 + jj] = f2bf(Wf[idx]);
  }
}

// ---------------- k_gather: slab-partitioned mean aggregation ----------------
// Block = 256 threads = 128 two-lane teams = 128 nodes, one 16-feat slab.
// slab = blockIdx&7 -> lands on XCD (blockIdx&7) -> slab stays L2-resident.
// Per team: preload 8 neighbor idx (nt), 8 unconditional 16B row loads
// (out-of-degree slots -> zero pad row NN), unpack-accumulate in packed f32
// pairs, rare tail loop for deg>8. col/deg nt-loaded, agg nt-stored so the
// 3.2MB slab isn't evicted from L2. No LDS, no barriers.
__global__ __launch_bounds__(256, 4)
void k_gather(const unsigned short* __restrict__ hT, unsigned short* __restrict__ aggB,
              const int* __restrict__ deg, const int* __restrict__ col) {
  const int b = blockIdx.x;
  const int s = b & 7;       // feature slab == XCD
  const int chunk = b >> 3;
  const int t = threadIdx.x;
  const int tm = t >> 1, half = t & 1;
  const int n = chunk * 128 + tm;
  if (n >= NN) return;  // tail chunk guard (no barriers in this kernel)
  const unsigned short* hs = hT + (size_t)s * NP1 * 16 + half * 8;
  int dg = __builtin_nontemporal_load(deg + n);
  int dc = min(dg, BCAP);
  const int* cp = col + (size_t)n * BCAP;
  int4v c0 = __builtin_nontemporal_load((const int4v*)cp);
  int4v c1 = __builtin_nontemporal_load((const int4v*)(cp + 4));

  f32x2 a[4];
  a[0] = 0.f; a[1] = 0.f; a[2] = 0.f; a[3] = 0.f;
  auto rowv = [&](int id) { return *(const uint4v*)(hs + (size_t)id * 16); };
  auto accv = [&](uint4v v) {
    a[0] += (f32x2){bflo(v.x), bfhi(v.x)};
    a[1] += (f32x2){bflo(v.y), bfhi(v.y)};
    a[2] += (f32x2){bflo(v.z), bfhi(v.z)};
    a[3] += (f32x2){bflo(v.w), bfhi(v.w)};
  };
  {  // first 8 neighbors: all loads issued before any accumulate
    uint4v v0 = rowv(0 < dc ? c0.x : NN);
    uint4v v1 = rowv(1 < dc ? c0.y : NN);
    uint4v v2 = rowv(2 < dc ? c0.z : NN);
    uint4v v3 = rowv(3 < dc ? c0.w : NN);
    uint4v v4 = rowv(4 < dc ? c1.x : NN);
    uint4v v5 = rowv(5 < dc ? c1.y : NN);
    uint4v v6 = rowv(6 < dc ? c1.z : NN);
    uint4v v7 = rowv(7 < dc ? c1.w : NN);
    accv(v0); accv(v1); accv(v2); accv(v3);
    accv(v4); accv(v5); accv(v6); accv(v7);
  }
  for (int j0 = 8; j0 < dc; j0 += 4) {  // 41% of nodes, exec-masked
    int4v c = __builtin_nontemporal_load((const int4v*)(cp + j0));
    uint4v v0 = rowv(j0 + 0 < dc ? c.x : NN);
    uint4v v1 = rowv(j0 + 1 < dc ? c.y : NN);
    uint4v v2 = rowv(j0 + 2 < dc ? c.z : NN);
    uint4v v3 = rowv(j0 + 3 < dc ? c.w : NN);
    accv(v0); accv(v1); accv(v2); accv(v3);
  }
  float inv = 1.f / fmaxf((float)dg, 1.f);
  unsigned int p0 = ((unsigned int)f2bf(a[0].y * inv) << 16) | f2bf(a[0].x * inv);
  unsigned int p1 = ((unsigned int)f2bf(a[1].y * inv) << 16) | f2bf(a[1].x * inv);
  unsigned int p2 = ((unsigned int)f2bf(a[2].y * inv) << 16) | f2bf(a[2].x * inv);
  unsigned int p3 = ((unsigned int)f2bf(a[3].y * inv) << 16) | f2bf(a[3].x * inv);
  uint4v pk = {p0, p1, p2, p3};
  // nt store: don't evict the gather slab; consecutive lanes -> contiguous 16B
  __builtin_nontemporal_store(pk, (uint4v*)(aggB + ((size_t)s * NP1 + n) * 16 + half * 8));
}

// ---------------- k_dense: z = agg*Wl^T + bl + h*Wr^T, LN, ReLU (+ head) ------------
// block = 128 threads (2 independent waves, no barriers), 32 nodes/block.
// agg + h A-frags are plain coalesced global loads (slab-major indexing);
// uniform work, stream + MFMA bound.
template <bool LAST>
__global__ __launch_bounds__(128, 4)
void k_dense(const unsigned short* __restrict__ hin, const unsigned short* __restrict__ agg,
             unsigned short* __restrict__ hout,
             const unsigned short* __restrict__ Wb, const float* __restrict__ bl,
             const float* __restrict__ gmm, const float* __restrict__ bta,
             const unsigned short* __restrict__ Wfb, const float* __restrict__ bfp,
             float* __restrict__ out) {
  __shared__ unsigned short hS[LAST ? 32 * 136 : 2];  // only LAST uses LDS
  const int t = threadIdx.x;
  const int w = t >> 6;
  const int lane = t & 63;
  const int nodeBase = blockIdx.x * 32;
  const int q = lane >> 4;
  const int n16 = lane & 15;

  // A-frags: row n16's agg + h, feats c*32 + q*8 .. +8  (slab s = 2c + (q>>1))
  const int node = nodeBase + w * 16 + n16;
  short8 a_h[4], a_agg[4];
#pragma unroll
  for (int c = 0; c < 4; ++c) {
    size_t e = ((size_t)(2 * c + (q >> 1)) * NP1 + node) * 16 + (q & 1) * 8;
    a_h[c] = *(const short8*)(hin + e);
    a_agg[c] = *(const short8*)(agg + e);
  }

  f32x4 acc[8];
#pragma unroll
  for (int jt = 0; jt < 8; ++jt) acc[jt] = (f32x4){0.f, 0.f, 0.f, 0.f};
#pragma unroll
  for (int c = 0; c < 4; ++c) {
#pragma unroll
    for (int jt = 0; jt < 8; ++jt) {
      short8 b_l = *(const short8*)(Wb + (c * 8 + jt) * 512 + lane * 8);
      short8 b_r = *(const short8*)(Wb + 16384 + (c * 8 + jt) * 512 + lane * 8);
      acc[jt] = __builtin_amdgcn_mfma_f32_16x16x32_bf16(a_agg[c], b_l, acc[jt], 0, 0, 0);
      acc[jt] = __builtin_amdgcn_mfma_f32_16x16x32_bf16(a_h[c], b_r, acc[jt], 0, 0, 0);
    }
  }

  // epilogue: +bias, LayerNorm (xor-shuffle over 16-lane groups), ReLU
  float blv[8], gv[8], bv[8];
#pragma unroll
  for (int jt = 0; jt < 8; ++jt) {
    int j = jt * 16 + n16;
    blv[jt] = bl[j];
    gv[jt] = gmm[j];
    bv[jt] = bta[j];
  }
  float s[4] = {0, 0, 0, 0}, ss[4] = {0, 0, 0, 0};
#pragma unroll
  for (int jt = 0; jt < 8; ++jt)
#pragma unroll
    for (int r = 0; r < 4; ++r) {
      float v = acc[jt][r] + blv[jt];
      acc[jt][r] = v;
      s[r] += v;
      ss[r] += v * v;
    }
#pragma unroll
  for (int mask = 1; mask < 16; mask <<= 1) {
#pragma unroll
    for (int r = 0; r < 4; ++r) {
      s[r] += __shfl_xor(s[r], mask, 64);
      ss[r] += __shfl_xor(ss[r], mask, 64);
    }
  }
  float mu[4], rs[4];
#pragma unroll
  for (int r = 0; r < 4; ++r) {
    mu[r] = s[r] * (1.f / 128.f);
    float var = ss[r] * (1.f / 128.f) - mu[r] * mu[r];
    rs[r] = rsqrtf(var + 1e-5f);
  }

  if (!LAST) {
#pragma unroll
    for (int jt = 0; jt < 8; ++jt)
#pragma unroll
      for (int r = 0; r < 4; ++r) {
        int n = nodeBase + w * 16 + q * 4 + r;
        float v = (acc[jt][r] - mu[r]) * rs[r] * gv[jt] + bv[jt];
        // feat = jt*16 + n16 -> slab jt
        hout[((size_t)jt * NP1 + n) * 16 + n16] = f2bf(fmaxf(v, 0.f));
      }
  } else {
#pragma unroll
    for (int jt = 0; jt < 8; ++jt)
#pragma unroll
      for (int r = 0; r < 4; ++r) {
        float v = (acc[jt][r] - mu[r]) * rs[r] * gv[jt] + bv[jt];
        hS[(w * 16 + q * 4 + r) * 136 + jt * 16 + n16] = f2bf(fmaxf(v, 0.f));
      }
    // final 128x64 GEMM + log_softmax (same-wave rows only; per-wave DS order)
    f32x4 acc2[4];
#pragma unroll
    for (int jt = 0; jt < 4; ++jt) acc2[jt] = (f32x4){0.f, 0.f, 0.f, 0.f};
#pragma unroll
    for (int c = 0; c < 4; ++c) {
      short8 a3 = *(const short8*)&hS[(w * 16 + n16) * 136 + c * 32 + q * 8];
#pragma unroll
      for (int jt = 0; jt < 4; ++jt) {
        short8 b = *(const short8*)(Wfb + (c * 4 + jt) * 512 + lane * 8);
        acc2[jt] = __builtin_amdgcn_mfma_f32_16x16x32_bf16(a3, b, acc2[jt], 0, 0, 0);
      }
    }
    float bfv[4];
#pragma unroll
    for (int jt = 0; jt < 4; ++jt) bfv[jt] = bfp[jt * 16 + n16];
    float mx[4] = {-1e30f, -1e30f, -1e30f, -1e30f};
#pragma unroll
    for (int jt = 0; jt < 4; ++jt)
#pragma unroll
      for (int r = 0; r < 4; ++r) {
        float v = acc2[jt][r] + bfv[jt];
        acc2[jt][r] = v;
        mx[r] = fmaxf(mx[r], v);
      }
#pragma unroll
    for (int mask = 1; mask < 16; mask <<= 1)
#pragma unroll
      for (int r = 0; r < 4; ++r) mx[r] = fmaxf(mx[r], __shfl_xor(mx[r], mask, 64));
    float se[4] = {0, 0, 0, 0};
#pragma unroll
    for (int jt = 0; jt < 4; ++jt)
#pragma unroll
      for (int r = 0; r < 4; ++r) se[r] += expf(acc2[jt][r] - mx[r]);
#pragma unroll
    for (int mask = 1; mask < 16; mask <<= 1)
#pragma unroll
      for (int r = 0; r < 4; ++r) se[r] += __shfl_xor(se[r], mask, 64);
    float lse[4];
#pragma unroll
    for (int r = 0; r < 4; ++r) lse[r] = mx[r] + logf(se[r]);
#pragma unroll
    for (int jt = 0; jt < 4; ++jt)
#pragma unroll
      for (int r = 0; r < 4; ++r) {
        int n = nodeBase + w * 16 + q * 4 + r;
        out[(size_t)n * 64 + jt * 16 + n16] = acc2[jt][r] - lse[r];
      }
  }
}

// ---------------- launch ----------------

extern "C" void kernel_launch(void* const* d_in, const int* in_sizes, int n_in,
                              void* d_out, int out_size, void* d_ws, size_t ws_size,
                              hipStream_t stream) {
  const float* x = (const float*)d_in[0];
  const int* ei = (const int*)d_in[1];
  const float* Wl = (const float*)d_in[2];
  const float* bl = (const float*)d_in[3];
  const float* Wr = (const float*)d_in[4];
  const float* gmm = (const float*)d_in[5];
  const float* bta = (const float*)d_in[6];
  const float* Wf = (const float*)d_in[7];
  const float* bfp = (const float*)d_in[8];

  char* ws = (char*)d_ws;
  size_t off = 0;
  auto alloc = [&](size_t bytes) {
    void* p = ws + off;
    off = (off + bytes + 255) & ~(size_t)255;
    return p;
  };
  int* cnt = (int*)alloc((size_t)(NN + 32) * 4);          // degree (atomic cursor)
  int* col = (int*)alloc((size_t)(NN + 32) * BCAP * 4);   // bucketed CSR
  // three slab-major h/agg buffers (hin / agg / hout rotate)
  unsigned short* hb0 = (unsigned short*)alloc((size_t)8 * NP1 * 32);
  unsigned short* hb1 = (unsigned short*)alloc((size_t)8 * NP1 * 32);
  unsigned short* hb2 = (unsigned short*)alloc((size_t)8 * NP1 * 32);
  unsigned short* Wb = (unsigned short*)alloc((size_t)3 * 32768 * 2);
  unsigned short* Wfb = (unsigned short*)alloc((size_t)8192 * 2);

  hipMemsetAsync(cnt, 0, (size_t)(NN + 32) * 4, stream);
  // +1 block so the pad-row zeroing branch (i >= NN*32) actually executes
  k_prep_fill<<<NN * 128 / 4 / 256 + 1, 256, 0, stream>>>(x, hb0, hb1, hb2, ei, cnt, col,
                                                          Wl, Wr, Wb, Wf, Wfb);

  const int GA = 8 * ((NN + 127) / 128);  // slabs x node-chunks

  k_gather<<<GA, 256, 0, stream>>>(hb0, hb1, cnt, col);
  k_dense<false><<<NBT, 128, 0, stream>>>(hb0, hb1, hb2, Wb, bl, gmm, bta, Wfb, bfp,
                                          (float*)d_out);
  k_gather<<<GA, 256, 0, stream>>>(hb2, hb0, cnt, col);
  k_dense<false><<<NBT, 128, 0, stream>>>(hb2, hb0, hb1, Wb + 32768, bl + 128,
                                          gmm + 128, bta + 128, Wfb, bfp, (float*)d_out);
  k_gather<<<GA, 256, 0, stream>>>(hb1, hb2, cnt, col);
  k_dense<true><<<NBT, 128, 0, stream>>>(hb1, hb2, hb0, Wb + 65536, bl + 256,
                                         gmm + 256, bta + 256, Wfb, bfp, (float*)d_out);
}